// Round 1
// baseline (1085.519 us; speedup 1.0000x reference)
//
#include <hip/hip_runtime.h>
#include <math.h>

constexpr int B = 2, L = 1024, D = 1024, H = 16, DK = 64;
constexpr int M = B * L;  // 2048 rows

// ---------------- LayerNorm (pre-LN on query) ----------------
__global__ __launch_bounds__(256) void ln_kernel(const float* __restrict__ x,
                                                 const float* __restrict__ gamma,
                                                 const float* __restrict__ beta,
                                                 float* __restrict__ y) {
    int row = blockIdx.x;
    int t = threadIdx.x;
    const float4 v = ((const float4*)(x + (size_t)row * D))[t];
    float s  = v.x + v.y + v.z + v.w;
    float sq = v.x*v.x + v.y*v.y + v.z*v.z + v.w*v.w;
    #pragma unroll
    for (int m = 32; m >= 1; m >>= 1) {
        s  += __shfl_xor(s, m, 64);
        sq += __shfl_xor(sq, m, 64);
    }
    __shared__ float rs[4], rq[4];
    int wid = t >> 6;
    if ((t & 63) == 0) { rs[wid] = s; rq[wid] = sq; }
    __syncthreads();
    s  = rs[0] + rs[1] + rs[2] + rs[3];
    sq = rq[0] + rq[1] + rq[2] + rq[3];
    float mean = s * (1.0f / D);
    float var  = sq * (1.0f / D) - mean * mean;
    float rstd = rsqrtf(var + 1e-6f);
    float4 g  = ((const float4*)gamma)[t];
    float4 bb = ((const float4*)beta)[t];
    float4 o;
    o.x = (v.x - mean) * rstd * g.x + bb.x;
    o.y = (v.y - mean) * rstd * g.y + bb.y;
    o.z = (v.z - mean) * rstd * g.z + bb.z;
    o.w = (v.w - mean) * rstd * g.w + bb.w;
    ((float4*)(y + (size_t)row * D))[t] = o;
}

// ---------------- fp32 GEMM: C[M,N] = A[M,K] @ W[N,K]^T + bias (+res) -------
// 64x64 tile per block (256 threads), BK=16, 4x4 accumulators per thread.
template<bool ADD_RES>
__global__ __launch_bounds__(256) void gemm_bt(const float* __restrict__ A,
                                               const float* __restrict__ W,
                                               const float* __restrict__ bias,
                                               const float* __restrict__ res,
                                               float* __restrict__ C,
                                               int Mm, int Nn, int Kk) {
    __shared__ float As[16][68];   // [k][m], pad 68 keeps float4 alignment
    __shared__ float Ws[16][68];   // [k][n]
    int t  = threadIdx.x;
    int tx = t & 15, ty = t >> 4;
    int bn = blockIdx.x * 64, bm = blockIdx.y * 64;
    int lr = t >> 2;          // 0..63 : row within tile
    int lc = (t & 3) * 4;     // 0,4,8,12 : k-offset (float4)
    float acc[4][4] = {};
    const float* Ap = A + (size_t)(bm + lr) * Kk + lc;
    const float* Wp = W + (size_t)(bn + lr) * Kk + lc;
    for (int k0 = 0; k0 < Kk; k0 += 16) {
        float4 a = *(const float4*)(Ap + k0);
        float4 w = *(const float4*)(Wp + k0);
        __syncthreads();   // previous tile's readers done
        As[lc+0][lr] = a.x; As[lc+1][lr] = a.y; As[lc+2][lr] = a.z; As[lc+3][lr] = a.w;
        Ws[lc+0][lr] = w.x; Ws[lc+1][lr] = w.y; Ws[lc+2][lr] = w.z; Ws[lc+3][lr] = w.w;
        __syncthreads();
        #pragma unroll
        for (int kk = 0; kk < 16; kk++) {
            float4 av = *(const float4*)&As[kk][ty * 4];
            float4 wv = *(const float4*)&Ws[kk][tx * 4];
            float ar[4] = {av.x, av.y, av.z, av.w};
            float wr[4] = {wv.x, wv.y, wv.z, wv.w};
            #pragma unroll
            for (int i = 0; i < 4; i++)
                #pragma unroll
                for (int j = 0; j < 4; j++)
                    acc[i][j] += ar[i] * wr[j];
        }
    }
    float4 bv = *(const float4*)&bias[bn + tx * 4];
    #pragma unroll
    for (int i = 0; i < 4; i++) {
        int m = bm + ty * 4 + i;
        float4 o;
        o.x = acc[i][0] + bv.x;
        o.y = acc[i][1] + bv.y;
        o.z = acc[i][2] + bv.z;
        o.w = acc[i][3] + bv.w;
        if (ADD_RES) {
            float4 r = *(const float4*)&res[(size_t)m * Nn + bn + tx * 4];
            o.x += r.x; o.y += r.y; o.z += r.z; o.w += r.w;
        }
        *(float4*)&C[(size_t)m * Nn + bn + tx * 4] = o;
    }
}

// ---------------- fused attention: logits+bias+mask -> softmax -> P@V -------
// One block per (b, h, 8-query tile). 256 threads.
__global__ __launch_bounds__(256) void attn_kernel(
        const float* __restrict__ Qm, const float* __restrict__ Km,
        const float* __restrict__ Vm,
        const float* __restrict__ pos_bias, const float* __restrict__ postag_bias,
        const float* __restrict__ lex_mask, const int* __restrict__ mask,
        float* __restrict__ attn_out, float* __restrict__ ctx) {
    constexpr int TQ = 8, TS = 64;
    __shared__ float q_sh[TQ][68];      // query rows (later reused as combine buf)
    __shared__ float kv_sh[TS][68];     // K or V tile
    __shared__ float pl[TQ][L];         // logits -> probs (32 KB)
    int t  = threadIdx.x;
    int qt = blockIdx.x & (L / TQ - 1); // q varies fastest -> L2 reuse of K/V slab
    int bh = blockIdx.x >> 7;
    int b  = bh >> 4, h = bh & 15;
    int q0 = qt * TQ;
    size_t base_bh = (size_t)b * L * D + (size_t)h * DK;  // + row*D to index [b,row,h,:]

    if (t < 128) {
        int r = t >> 4, c = t & 15;
        *(float4*)&q_sh[r][4 * c] =
            *(const float4*)&Qm[base_bh + (size_t)(q0 + r) * D + 4 * c];
    }

    int qrow = t >> 5, l = t & 31;      // 32-lane group per q-row
    // ---- phase A: logits = QK^T/8 + biases, masked ----
    for (int st = 0; st < L; st += TS) {
        __syncthreads();
        #pragma unroll
        for (int i = 0; i < 4; i++) {
            int idx = t + 256 * i;
            int r = idx >> 4, c = idx & 15;
            *(float4*)&kv_sh[r][4 * c] =
                *(const float4*)&Km[base_bh + (size_t)(st + r) * D + 4 * c];
        }
        __syncthreads();
        float dot0 = 0.f, dot1 = 0.f;
        #pragma unroll
        for (int c = 0; c < 16; c++) {
            float4 qv = *(const float4*)&q_sh[qrow][4 * c];
            float4 k0 = *(const float4*)&kv_sh[l][4 * c];
            float4 k1 = *(const float4*)&kv_sh[l + 32][4 * c];
            dot0 += qv.x*k0.x + qv.y*k0.y + qv.z*k0.z + qv.w*k0.w;
            dot1 += qv.x*k1.x + qv.y*k1.y + qv.z*k1.z + qv.w*k1.w;
        }
        int qg = q0 + qrow;
        #pragma unroll
        for (int j = 0; j < 2; j++) {
            int s = st + l + 32 * j;
            float dv = (j == 0) ? dot0 : dot1;
            float lg = dv * 0.125f
                     + pos_bias[((size_t)h * L + qg) * L + s]
                     + postag_bias[((size_t)bh * L + qg) * L + s]
                     + lex_mask[b * L + s];
            if (mask[b * L + s] == 0) lg = -INFINITY;
            pl[qrow][s] = lg;
        }
    }
    __syncthreads();
    // ---- softmax along s (stable), write attn output ----
    {
        float mx = -INFINITY;
        for (int s = l; s < L; s += 32) mx = fmaxf(mx, pl[qrow][s]);
        #pragma unroll
        for (int m = 16; m >= 1; m >>= 1) mx = fmaxf(mx, __shfl_xor(mx, m, 32));
        float sum = 0.f;
        for (int s = l; s < L; s += 32) {
            float v = pl[qrow][s];
            float e = (v == -INFINITY) ? 0.f : __expf(v - mx);
            pl[qrow][s] = e;
            sum += e;
        }
        #pragma unroll
        for (int m = 16; m >= 1; m >>= 1) sum += __shfl_xor(sum, m, 32);
        float inv = 1.0f / sum;
        size_t arow = ((size_t)bh * L + (q0 + qrow)) * (size_t)L;
        for (int s = l; s < L; s += 32) {
            float p = pl[qrow][s] * inv;
            pl[qrow][s] = p;
            attn_out[arow + s] = p;
        }
    }
    // ---- phase B: ctx = P @ V ----
    int d4  = (t & 15) * 4;       // dk offset (float4)
    int qb  = (t >> 4) & 7;       // q row
    int rep = t >> 7;             // s-half split
    float4 acc = {0.f, 0.f, 0.f, 0.f};
    for (int st = 0; st < L; st += TS) {
        __syncthreads();
        #pragma unroll
        for (int i = 0; i < 4; i++) {
            int idx = t + 256 * i;
            int r = idx >> 4, c = idx & 15;
            *(float4*)&kv_sh[r][4 * c] =
                *(const float4*)&Vm[base_bh + (size_t)(st + r) * D + 4 * c];
        }
        __syncthreads();
        int sb = rep * 32;
        #pragma unroll
        for (int s4 = 0; s4 < 8; s4++) {
            float4 pv = *(const float4*)&pl[qb][st + sb + 4 * s4];
            float pw[4] = {pv.x, pv.y, pv.z, pv.w};
            #pragma unroll
            for (int u = 0; u < 4; u++) {
                float4 vv = *(const float4*)&kv_sh[sb + 4 * s4 + u][d4];
                acc.x += pw[u] * vv.x; acc.y += pw[u] * vv.y;
                acc.z += pw[u] * vv.z; acc.w += pw[u] * vv.w;
            }
        }
    }
    __syncthreads();
    if (rep == 1) *(float4*)&q_sh[qb][d4] = acc;   // q_sh reused as combine buffer
    __syncthreads();
    if (rep == 0) {
        float4 o = *(const float4*)&q_sh[qb][d4];
        o.x += acc.x; o.y += acc.y; o.z += acc.z; o.w += acc.w;
        *(float4*)&ctx[base_bh + (size_t)(q0 + qb) * D + d4] = o;
    }
}

extern "C" void kernel_launch(void* const* d_in, const int* in_sizes, int n_in,
                              void* d_out, int out_size, void* d_ws, size_t ws_size,
                              hipStream_t stream) {
    (void)in_sizes; (void)n_in; (void)out_size; (void)ws_size;
    const float* query  = (const float*)d_in[0];
    const float* pos_b  = (const float*)d_in[1];
    const float* postag = (const float*)d_in[2];
    const float* lex    = (const float*)d_in[3];
    const int*   mask   = (const int*)d_in[4];
    const float* Wq = (const float*)d_in[5];
    const float* bq = (const float*)d_in[6];
    const float* Wk = (const float*)d_in[7];
    const float* bk = (const float*)d_in[8];
    const float* Wv = (const float*)d_in[9];
    const float* bv = (const float*)d_in[10];
    const float* Wo = (const float*)d_in[11];
    const float* bo = (const float*)d_in[12];
    const float* gamma = (const float*)d_in[13];
    const float* beta  = (const float*)d_in[14];

    float* out  = (float*)d_out;                 // (B,L,D)
    float* attn = out + (size_t)B * L * D;       // (B,H,L,L)

    // workspace: 5 x 8 MB fp32 buffers (qn, Q, K, V, ctx) = 40 MB
    float* ws = (float*)d_ws;
    const size_t NE = (size_t)B * L * D;
    float* qn  = ws;
    float* Qm  = ws + NE;
    float* Km  = ws + 2 * NE;
    float* Vm  = ws + 3 * NE;
    float* ctx = ws + 4 * NE;

    ln_kernel<<<M, 256, 0, stream>>>(query, gamma, beta, qn);
    dim3 gg(D / 64, M / 64);
    gemm_bt<false><<<gg, 256, 0, stream>>>(qn,    Wq, bq, nullptr, Qm, M, D, D);
    gemm_bt<false><<<gg, 256, 0, stream>>>(query, Wk, bk, nullptr, Km, M, D, D);
    gemm_bt<false><<<gg, 256, 0, stream>>>(query, Wv, bv, nullptr, Vm, M, D, D);
    attn_kernel<<<B * H * (L / 8), 256, 0, stream>>>(Qm, Km, Vm, pos_b, postag,
                                                     lex, mask, attn, ctx);
    gemm_bt<true><<<gg, 256, 0, stream>>>(ctx, Wo, bo, query, out, M, D, D);
}

// Round 2
// 696.410 us; speedup vs baseline: 1.5587x; 1.5587x over previous
//
#include <hip/hip_runtime.h>
#include <hip/hip_bf16.h>
#include <math.h>

constexpr int B = 2, L = 1024, D = 1024, H = 16, DK = 64;
constexpr int M = B * L;           // 2048 rows
constexpr int DD = D * D;

typedef __attribute__((ext_vector_type(8))) short bf16x8;
typedef __attribute__((ext_vector_type(4))) float f32x4;

__device__ inline unsigned short f2bf(float f) {
    __hip_bfloat16 h = __float2bfloat16(f);
    return __builtin_bit_cast(unsigned short, h);
}

// ---------------- LayerNorm: qn16 = LN(query) bf16, q16 = bf16(query) -------
__global__ __launch_bounds__(256) void ln2_kernel(const float* __restrict__ x,
                                                  const float* __restrict__ gamma,
                                                  const float* __restrict__ beta,
                                                  unsigned short* __restrict__ qn16,
                                                  unsigned short* __restrict__ q16) {
    int row = blockIdx.x;
    int t = threadIdx.x;
    const float4 v = ((const float4*)(x + (size_t)row * D))[t];
    float s  = v.x + v.y + v.z + v.w;
    float sq = v.x*v.x + v.y*v.y + v.z*v.z + v.w*v.w;
    #pragma unroll
    for (int m = 32; m >= 1; m >>= 1) {
        s  += __shfl_xor(s, m, 64);
        sq += __shfl_xor(sq, m, 64);
    }
    __shared__ float rs[4], rq[4];
    int wid = t >> 6;
    if ((t & 63) == 0) { rs[wid] = s; rq[wid] = sq; }
    __syncthreads();
    s  = rs[0] + rs[1] + rs[2] + rs[3];
    sq = rq[0] + rq[1] + rq[2] + rq[3];
    float mean = s * (1.0f / D);
    float var  = sq * (1.0f / D) - mean * mean;
    float rstd = rsqrtf(var + 1e-6f);
    float4 g  = ((const float4*)gamma)[t];
    float4 bb = ((const float4*)beta)[t];
    ushort4 on, oq;
    on.x = f2bf((v.x - mean) * rstd * g.x + bb.x);
    on.y = f2bf((v.y - mean) * rstd * g.y + bb.y);
    on.z = f2bf((v.z - mean) * rstd * g.z + bb.z);
    on.w = f2bf((v.w - mean) * rstd * g.w + bb.w);
    oq.x = f2bf(v.x); oq.y = f2bf(v.y); oq.z = f2bf(v.z); oq.w = f2bf(v.w);
    ((ushort4*)(qn16 + (size_t)row * D))[t] = on;
    ((ushort4*)(q16  + (size_t)row * D))[t] = oq;
}

// ---------------- weight cast: 4 x (D,D) fp32 -> bf16 ----------------------
__global__ __launch_bounds__(256) void wconv_kernel(const float* __restrict__ Wq,
                                                    const float* __restrict__ Wk,
                                                    const float* __restrict__ Wv,
                                                    const float* __restrict__ Wo,
                                                    unsigned short* __restrict__ out) {
    const float* src = (blockIdx.y == 0) ? Wq : (blockIdx.y == 1) ? Wk
                       : (blockIdx.y == 2) ? Wv : Wo;
    size_t i = (size_t)blockIdx.x * 256 + threadIdx.x;   // float4 index
    float4 v = ((const float4*)src)[i];
    ushort4 o;
    o.x = f2bf(v.x); o.y = f2bf(v.y); o.z = f2bf(v.z); o.w = f2bf(v.w);
    ((ushort4*)(out + (size_t)blockIdx.y * DD))[i] = o;
}

// ---------------- bf16 MFMA GEMM: C[M,N] = A[M,K] @ W[N,K]^T + bias (+res) -
// 64x64 tile, 4 waves in 2x2, each wave 32x32 (2x2 MFMA tiles), BK=64.
template<bool OUT_BF16, bool ADD_RES>
__global__ __launch_bounds__(256) void gemm16(const unsigned short* __restrict__ A,
                                              const unsigned short* __restrict__ W,
                                              const float* __restrict__ bias,
                                              const float* __restrict__ res,
                                              void* __restrict__ Cv,
                                              int Mm, int Nn, int Kk) {
    __shared__ __align__(16) unsigned short As[64][72];
    __shared__ __align__(16) unsigned short Ws[64][72];
    int t = threadIdx.x, lane = t & 63, w = t >> 6;
    int quad = lane >> 4, l15 = lane & 15;
    int bm = blockIdx.y * 64, bn = blockIdx.x * 64;
    int wm = (w >> 1) * 32, wn = (w & 1) * 32;
    f32x4 acc[2][2] = {};
    for (int k0 = 0; k0 < Kk; k0 += 64) {
        __syncthreads();
        #pragma unroll
        for (int i = 0; i < 2; i++) {
            int idx = t + 256 * i;          // 0..511
            int r = idx >> 3, c8 = idx & 7;
            *(uint4*)&As[r][c8 * 8] = *(const uint4*)&A[(size_t)(bm + r) * Kk + k0 + c8 * 8];
            *(uint4*)&Ws[r][c8 * 8] = *(const uint4*)&W[(size_t)(bn + r) * Kk + k0 + c8 * 8];
        }
        __syncthreads();
        #pragma unroll
        for (int k2 = 0; k2 < 2; k2++) {
            bf16x8 a0 = *(const bf16x8*)&As[wm + l15][k2 * 32 + quad * 8];
            bf16x8 a1 = *(const bf16x8*)&As[wm + 16 + l15][k2 * 32 + quad * 8];
            bf16x8 b0 = *(const bf16x8*)&Ws[wn + l15][k2 * 32 + quad * 8];
            bf16x8 b1 = *(const bf16x8*)&Ws[wn + 16 + l15][k2 * 32 + quad * 8];
            acc[0][0] = __builtin_amdgcn_mfma_f32_16x16x32_bf16(a0, b0, acc[0][0], 0, 0, 0);
            acc[0][1] = __builtin_amdgcn_mfma_f32_16x16x32_bf16(a0, b1, acc[0][1], 0, 0, 0);
            acc[1][0] = __builtin_amdgcn_mfma_f32_16x16x32_bf16(a1, b0, acc[1][0], 0, 0, 0);
            acc[1][1] = __builtin_amdgcn_mfma_f32_16x16x32_bf16(a1, b1, acc[1][1], 0, 0, 0);
        }
    }
    #pragma unroll
    for (int i = 0; i < 2; i++)
        #pragma unroll
        for (int j = 0; j < 2; j++)
            #pragma unroll
            for (int rg = 0; rg < 4; rg++) {
                int row = bm + wm + i * 16 + quad * 4 + rg;
                int col = bn + wn + j * 16 + l15;
                float v = acc[i][j][rg] + bias[col];
                if (ADD_RES) v += res[(size_t)row * Nn + col];
                if (OUT_BF16) ((unsigned short*)Cv)[(size_t)row * Nn + col] = f2bf(v);
                else          ((float*)Cv)[(size_t)row * Nn + col] = v;
            }
}

// ---------------- MFMA attention -------------------------------------------
// Block: one (b,h) x 16-query tile. 256 threads (4 waves). Logits in MFMA
// accumulators (16 tiles x f32x4 = 64 VGPR). Wave w owns s-tiles nt = 4t+w.
__global__ __launch_bounds__(256) void attn2_kernel(
        const unsigned short* __restrict__ Qm, const unsigned short* __restrict__ Km,
        const unsigned short* __restrict__ Vm,
        const float* __restrict__ pos_bias, const float* __restrict__ postag,
        const float* __restrict__ lex, const int* __restrict__ mask,
        float* __restrict__ attn_out, unsigned short* __restrict__ ctx16) {
    __shared__ __align__(16) unsigned short q_sh[16][72];
    __shared__ __align__(16) unsigned short kv_sh[128][72];   // K tiles / reused for V^T
    __shared__ __align__(16) unsigned short p_sh[16][1032];
    __shared__ float redA[16][4], redB[16][4];

    int t = threadIdx.x, lane = t & 63, w = t >> 6;
    int quad = lane >> 4, l15 = lane & 15;
    int qt = blockIdx.x & 63;
    int bh = blockIdx.x >> 6;
    int b = bh >> 4, h = bh & 15;
    int q0 = qt * 16;
    size_t base = (size_t)b * L * D + (size_t)h * DK;

    if (t < 128) {
        int r = t >> 3, c8 = t & 7;
        *(uint4*)&q_sh[r][c8 * 8] = *(const uint4*)&Qm[base + (size_t)(q0 + r) * D + c8 * 8];
    }
    __syncthreads();
    bf16x8 a0 = *(const bf16x8*)&q_sh[l15][quad * 8];
    bf16x8 a1 = *(const bf16x8*)&q_sh[l15][32 + quad * 8];

    f32x4 acc[16] = {};
    // ---- phase A: S = Q K^T via MFMA, 8 stages of 128 keys ----
    for (int st = 0; st < 8; st++) {
        __syncthreads();
        #pragma unroll
        for (int i = 0; i < 4; i++) {
            int idx = t + 256 * i;          // 0..1023
            int r = idx >> 3, c8 = idx & 7;
            *(uint4*)&kv_sh[r][c8 * 8] =
                *(const uint4*)&Km[base + (size_t)(st * 128 + r) * D + c8 * 8];
        }
        __syncthreads();
        #pragma unroll
        for (int u = 0; u < 2; u++) {
            int lrow = (w + 4 * u) * 16;
            bf16x8 b0 = *(const bf16x8*)&kv_sh[lrow + l15][quad * 8];
            bf16x8 b1 = *(const bf16x8*)&kv_sh[lrow + l15][32 + quad * 8];
            int ti = 2 * st + u;
            acc[ti] = __builtin_amdgcn_mfma_f32_16x16x32_bf16(a0, b0, acc[ti], 0, 0, 0);
            acc[ti] = __builtin_amdgcn_mfma_f32_16x16x32_bf16(a1, b1, acc[ti], 0, 0, 0);
        }
    }
    // ---- biases + mask (lane holds q = quad*4+rg, s = nt*16 + l15) ----
    #pragma unroll
    for (int ti = 0; ti < 16; ti++) {
        int nt = (ti >> 1) * 8 + 4 * (ti & 1) + w;
        int s = nt * 16 + l15;
        float lx = lex[b * L + s];
        bool dead = (mask[b * L + s] == 0);
        #pragma unroll
        for (int rg = 0; rg < 4; rg++) {
            int q = q0 + quad * 4 + rg;
            float lg = acc[ti][rg] * 0.125f
                     + pos_bias[((size_t)h * L + q) * L + s]
                     + postag[((size_t)bh * L + q) * L + s] + lx;
            acc[ti][rg] = dead ? -INFINITY : lg;
        }
    }
    // ---- softmax over s (regs + 16-lane shuffle + cross-wave LDS) ----
    float mxv[4], inv_s[4];
    #pragma unroll
    for (int rg = 0; rg < 4; rg++) {
        float mx = -INFINITY;
        #pragma unroll
        for (int ti = 0; ti < 16; ti++) mx = fmaxf(mx, acc[ti][rg]);
        #pragma unroll
        for (int m = 1; m <= 8; m <<= 1) mx = fmaxf(mx, __shfl_xor(mx, m, 64));
        if (l15 == 0) redA[quad * 4 + rg][w] = mx;
    }
    __syncthreads();
    #pragma unroll
    for (int rg = 0; rg < 4; rg++) {
        int q = quad * 4 + rg;
        mxv[rg] = fmaxf(fmaxf(redA[q][0], redA[q][1]), fmaxf(redA[q][2], redA[q][3]));
        float sum = 0.f;
        #pragma unroll
        for (int ti = 0; ti < 16; ti++) {
            float e = __expf(acc[ti][rg] - mxv[rg]);
            acc[ti][rg] = e;
            sum += e;
        }
        #pragma unroll
        for (int m = 1; m <= 8; m <<= 1) sum += __shfl_xor(sum, m, 64);
        if (l15 == 0) redB[q][w] = sum;
    }
    __syncthreads();
    #pragma unroll
    for (int rg = 0; rg < 4; rg++) {
        int q = quad * 4 + rg;
        inv_s[rg] = 1.0f / (redB[q][0] + redB[q][1] + redB[q][2] + redB[q][3]);
    }
    // ---- write probs: fp32 to global attn, bf16 to LDS for PV ----
    #pragma unroll
    for (int ti = 0; ti < 16; ti++) {
        int nt = (ti >> 1) * 8 + 4 * (ti & 1) + w;
        int s = nt * 16 + l15;
        #pragma unroll
        for (int rg = 0; rg < 4; rg++) {
            int q = quad * 4 + rg;
            float p = acc[ti][rg] * inv_s[rg];
            attn_out[((size_t)bh * L + q0 + q) * L + s] = p;
            p_sh[q][s] = f2bf(p);
        }
    }
    // ---- phase B: ctx = P @ V (V^T staged via LDS transpose) ----
    unsigned short (*vt)[136] = (unsigned short (*)[136])kv_sh;   // [64][136]
    f32x4 oacc = {};
    for (int st = 0; st < 8; st++) {
        __syncthreads();
        #pragma unroll
        for (int i = 0; i < 4; i++) {
            int idx = t + 256 * i;
            int r = idx >> 3, c8 = idx & 7;
            uint4 raw = *(const uint4*)&Vm[base + (size_t)(st * 128 + r) * D + c8 * 8];
            const unsigned short* v8 = (const unsigned short*)&raw;
            #pragma unroll
            for (int j = 0; j < 8; j++) vt[c8 * 8 + j][r] = v8[j];
        }
        __syncthreads();
        #pragma unroll
        for (int k4 = 0; k4 < 4; k4++) {
            bf16x8 pa = *(const bf16x8*)&p_sh[l15][st * 128 + k4 * 32 + quad * 8];
            bf16x8 vb = *(const bf16x8*)&vt[w * 16 + l15][k4 * 32 + quad * 8];
            oacc = __builtin_amdgcn_mfma_f32_16x16x32_bf16(pa, vb, oacc, 0, 0, 0);
        }
    }
    #pragma unroll
    for (int rg = 0; rg < 4; rg++) {
        int q = q0 + quad * 4 + rg;
        ctx16[base + (size_t)q * D + w * 16 + l15] = f2bf(oacc[rg]);
    }
}

extern "C" void kernel_launch(void* const* d_in, const int* in_sizes, int n_in,
                              void* d_out, int out_size, void* d_ws, size_t ws_size,
                              hipStream_t stream) {
    (void)in_sizes; (void)n_in; (void)out_size; (void)ws_size;
    const float* query  = (const float*)d_in[0];
    const float* pos_b  = (const float*)d_in[1];
    const float* postag = (const float*)d_in[2];
    const float* lex    = (const float*)d_in[3];
    const int*   mask   = (const int*)d_in[4];
    const float* Wq = (const float*)d_in[5];
    const float* bq = (const float*)d_in[6];
    const float* Wk = (const float*)d_in[7];
    const float* bk = (const float*)d_in[8];
    const float* Wv = (const float*)d_in[9];
    const float* bv = (const float*)d_in[10];
    const float* Wo = (const float*)d_in[11];
    const float* bo = (const float*)d_in[12];
    const float* gamma = (const float*)d_in[13];
    const float* beta  = (const float*)d_in[14];

    float* out  = (float*)d_out;                 // (B,L,D)
    float* attn = out + (size_t)B * L * D;       // (B,H,L,L)

    // bf16 workspace: qn,q,Q,K,V,ctx (M*D each) + 4 weights (D*D each) = 32 MB
    unsigned short* ws16 = (unsigned short*)d_ws;
    const size_t NE = (size_t)M * D;
    unsigned short* qn16  = ws16;
    unsigned short* q16   = ws16 + NE;
    unsigned short* W16   = ws16 + 2 * NE;       // 4*DD
    unsigned short* Qm16  = W16 + 4 * (size_t)DD;
    unsigned short* Km16  = Qm16 + NE;
    unsigned short* Vm16  = Km16 + NE;
    unsigned short* ctx16 = Vm16 + NE;

    ln2_kernel<<<M, 256, 0, stream>>>(query, gamma, beta, qn16, q16);
    wconv_kernel<<<dim3(DD / 1024, 4), 256, 0, stream>>>(Wq, Wk, Wv, Wo, W16);
    dim3 gg(D / 64, M / 64);
    gemm16<true, false><<<gg, 256, 0, stream>>>(qn16, W16,          bq, nullptr, Qm16, M, D, D);
    gemm16<true, false><<<gg, 256, 0, stream>>>(q16,  W16 + DD,     bk, nullptr, Km16, M, D, D);
    gemm16<true, false><<<gg, 256, 0, stream>>>(q16,  W16 + 2 * DD, bv, nullptr, Vm16, M, D, D);
    attn2_kernel<<<B * H * (L / 16), 256, 0, stream>>>(Qm16, Km16, Vm16, pos_b,
                                                       postag, lex, mask, attn, ctx16);
    gemm16<false, true><<<gg, 256, 0, stream>>>(ctx16, W16 + 3 * DD, bo, query, out, M, D, D);
}

// Round 3
// 532.657 us; speedup vs baseline: 2.0379x; 1.3074x over previous
//
#include <hip/hip_runtime.h>
#include <hip/hip_bf16.h>
#include <math.h>

constexpr int B = 2, L = 1024, D = 1024, H = 16, DK = 64;
constexpr int M = B * L;           // 2048 rows
constexpr int DD = D * D;

typedef __attribute__((ext_vector_type(8))) short bf16x8;
typedef __attribute__((ext_vector_type(4))) float f32x4;

__device__ inline unsigned short f2bf(float f) {
    __hip_bfloat16 h = __float2bfloat16(f);
    return __builtin_bit_cast(unsigned short, h);
}

// ---------------- LayerNorm: qn16 = LN(query) bf16, q16 = bf16(query) -------
__global__ __launch_bounds__(256) void ln2_kernel(const float* __restrict__ x,
                                                  const float* __restrict__ gamma,
                                                  const float* __restrict__ beta,
                                                  unsigned short* __restrict__ qn16,
                                                  unsigned short* __restrict__ q16) {
    int row = blockIdx.x;
    int t = threadIdx.x;
    const float4 v = ((const float4*)(x + (size_t)row * D))[t];
    float s  = v.x + v.y + v.z + v.w;
    float sq = v.x*v.x + v.y*v.y + v.z*v.z + v.w*v.w;
    #pragma unroll
    for (int m = 32; m >= 1; m >>= 1) {
        s  += __shfl_xor(s, m, 64);
        sq += __shfl_xor(sq, m, 64);
    }
    __shared__ float rs[4], rq[4];
    int wid = t >> 6;
    if ((t & 63) == 0) { rs[wid] = s; rq[wid] = sq; }
    __syncthreads();
    s  = rs[0] + rs[1] + rs[2] + rs[3];
    sq = rq[0] + rq[1] + rq[2] + rq[3];
    float mean = s * (1.0f / D);
    float var  = sq * (1.0f / D) - mean * mean;
    float rstd = rsqrtf(var + 1e-6f);
    float4 g  = ((const float4*)gamma)[t];
    float4 bb = ((const float4*)beta)[t];
    ushort4 on, oq;
    on.x = f2bf((v.x - mean) * rstd * g.x + bb.x);
    on.y = f2bf((v.y - mean) * rstd * g.y + bb.y);
    on.z = f2bf((v.z - mean) * rstd * g.z + bb.z);
    on.w = f2bf((v.w - mean) * rstd * g.w + bb.w);
    oq.x = f2bf(v.x); oq.y = f2bf(v.y); oq.z = f2bf(v.z); oq.w = f2bf(v.w);
    ((ushort4*)(qn16 + (size_t)row * D))[t] = on;
    ((ushort4*)(q16  + (size_t)row * D))[t] = oq;
}

// ---------------- weight cast: 4 x (D,D) fp32 -> bf16 ----------------------
__global__ __launch_bounds__(256) void wconv_kernel(const float* __restrict__ Wq,
                                                    const float* __restrict__ Wk,
                                                    const float* __restrict__ Wv,
                                                    const float* __restrict__ Wo,
                                                    unsigned short* __restrict__ out) {
    const float* src = (blockIdx.y == 0) ? Wq : (blockIdx.y == 1) ? Wk
                       : (blockIdx.y == 2) ? Wv : Wo;
    size_t i = (size_t)blockIdx.x * 256 + threadIdx.x;   // float4 index
    float4 v = ((const float4*)src)[i];
    ushort4 o;
    o.x = f2bf(v.x); o.y = f2bf(v.y); o.z = f2bf(v.z); o.w = f2bf(v.w);
    ((ushort4*)(out + (size_t)blockIdx.y * DD))[i] = o;
}

// ---------------- fused QKV GEMM: 128x128 tile, BK=64 ----------------------
// W16 = [Wq;Wk;Wv] stacked (3072 x 1024). n-tile 0..23 selects A and output.
__global__ __launch_bounds__(256) void gemm_qkv(
        const unsigned short* __restrict__ qn16, const unsigned short* __restrict__ q16,
        const unsigned short* __restrict__ W,
        const float* __restrict__ bq, const float* __restrict__ bk,
        const float* __restrict__ bv,
        unsigned short* __restrict__ Qm, unsigned short* __restrict__ Km,
        unsigned short* __restrict__ Vm) {
    __shared__ __align__(16) unsigned short As[128][72];
    __shared__ __align__(16) unsigned short Ws[128][72];
    int t = threadIdx.x, lane = t & 63, w = t >> 6;
    int quad = lane >> 4, l15 = lane & 15;
    int nt = blockIdx.x;                 // 0..23
    int bm = blockIdx.y * 128;
    const unsigned short* A = (nt < 8) ? qn16 : q16;
    const float* bias = (nt < 8) ? bq : ((nt < 16) ? bk : bv);
    unsigned short* Cout = (nt < 8) ? Qm : ((nt < 16) ? Km : Vm);
    int bn_local = (nt & 7) * 128;
    int wm = (w >> 1) * 64, wn = (w & 1) * 64;
    int r0 = t >> 3, c8 = t & 7;
    f32x4 acc[4][4] = {};
    for (int k0 = 0; k0 < D; k0 += 64) {
        __syncthreads();
        #pragma unroll
        for (int i = 0; i < 4; i++) {
            int rr = r0 + 32 * i;
            *(uint4*)&As[rr][c8 * 8] = *(const uint4*)&A[(size_t)(bm + rr) * D + k0 + c8 * 8];
            *(uint4*)&Ws[rr][c8 * 8] = *(const uint4*)&W[(size_t)(nt * 128 + rr) * D + k0 + c8 * 8];
        }
        __syncthreads();
        #pragma unroll
        for (int k2 = 0; k2 < 64; k2 += 32) {
            bf16x8 av[4], bw[4];
            #pragma unroll
            for (int i = 0; i < 4; i++)
                av[i] = *(const bf16x8*)&As[wm + i * 16 + l15][k2 + quad * 8];
            #pragma unroll
            for (int j = 0; j < 4; j++)
                bw[j] = *(const bf16x8*)&Ws[wn + j * 16 + l15][k2 + quad * 8];
            #pragma unroll
            for (int i = 0; i < 4; i++)
                #pragma unroll
                for (int j = 0; j < 4; j++)
                    acc[i][j] = __builtin_amdgcn_mfma_f32_16x16x32_bf16(av[i], bw[j], acc[i][j], 0, 0, 0);
        }
    }
    #pragma unroll
    for (int j = 0; j < 4; j++) {
        int col = bn_local + wn + j * 16 + l15;
        float bcol = bias[col];
        #pragma unroll
        for (int i = 0; i < 4; i++)
            #pragma unroll
            for (int rg = 0; rg < 4; rg++) {
                int row = bm + wm + i * 16 + quad * 4 + rg;
                Cout[(size_t)row * D + col] = f2bf(acc[i][j][rg] + bcol);
            }
    }
}

// ---------------- V transpose: Vm [b,s,h*64+d] -> Vt [bh][d][s] ------------
__global__ __launch_bounds__(256) void vtrans_kernel(const unsigned short* __restrict__ Vm,
                                                     unsigned short* __restrict__ Vt) {
    __shared__ unsigned short sb[128 * 66];   // pitch 66 (odd dword rotation)
    int t = threadIdx.x;
    int z = blockIdx.y;                       // bh
    int b = z >> 4, h = z & 15;
    int s0 = blockIdx.x * 128;
    size_t base = (size_t)b * L * D + (size_t)h * 64;
    #pragma unroll
    for (int i = 0; i < 4; i++) {
        int idx = t + 256 * i;                // 0..1023
        int r = idx >> 3, c8 = idx & 7;
        uint4 vv = *(const uint4*)&Vm[base + (size_t)(s0 + r) * D + c8 * 8];
        unsigned int* sp = (unsigned int*)&sb[r * 66 + c8 * 8];
        sp[0] = vv.x; sp[1] = vv.y; sp[2] = vv.z; sp[3] = vv.w;
    }
    __syncthreads();
    #pragma unroll
    for (int i = 0; i < 4; i++) {
        int idx = t + 256 * i;                // 0..1023
        int d = idx >> 4, sc = idx & 15;
        unsigned short tmp[8];
        #pragma unroll
        for (int j = 0; j < 8; j++) tmp[j] = sb[(sc * 8 + j) * 66 + d];
        *(uint4*)&Vt[((size_t)z * 64 + d) * L + s0 + sc * 8] = *(uint4*)tmp;
    }
}

// ---------------- attention: QK^T + bias + mask + softmax -> attn (fp32) ----
__global__ __launch_bounds__(256) void attn3_kernel(
        const unsigned short* __restrict__ Qm, const unsigned short* __restrict__ Km,
        const float* __restrict__ pos_bias, const float* __restrict__ postag,
        const float* __restrict__ lex, const int* __restrict__ mask,
        float* __restrict__ attn_out) {
    __shared__ __align__(16) unsigned short q_sh[16][72];
    __shared__ __align__(16) unsigned short kv_sh[128][72];
    __shared__ float redA[16][4], redB[16][4];

    int t = threadIdx.x, lane = t & 63, w = t >> 6;
    int quad = lane >> 4, l15 = lane & 15;
    int qt = blockIdx.x & 63;
    int bh = blockIdx.x >> 6;
    int b = bh >> 4, h = bh & 15;
    int q0 = qt * 16;
    size_t base = (size_t)b * L * D + (size_t)h * DK;

    if (t < 128) {
        int r = t >> 3, c8 = t & 7;
        *(uint4*)&q_sh[r][c8 * 8] = *(const uint4*)&Qm[base + (size_t)(q0 + r) * D + c8 * 8];
    }
    __syncthreads();
    bf16x8 a0 = *(const bf16x8*)&q_sh[l15][quad * 8];
    bf16x8 a1 = *(const bf16x8*)&q_sh[l15][32 + quad * 8];

    f32x4 acc[16] = {};
    for (int st = 0; st < 8; st++) {
        __syncthreads();
        #pragma unroll
        for (int i = 0; i < 4; i++) {
            int idx = t + 256 * i;
            int r = idx >> 3, c8 = idx & 7;
            *(uint4*)&kv_sh[r][c8 * 8] =
                *(const uint4*)&Km[base + (size_t)(st * 128 + r) * D + c8 * 8];
        }
        __syncthreads();
        #pragma unroll
        for (int u = 0; u < 2; u++) {
            int lrow = (w + 4 * u) * 16;
            bf16x8 b0 = *(const bf16x8*)&kv_sh[lrow + l15][quad * 8];
            bf16x8 b1 = *(const bf16x8*)&kv_sh[lrow + l15][32 + quad * 8];
            int ti = 2 * st + u;
            acc[ti] = __builtin_amdgcn_mfma_f32_16x16x32_bf16(a0, b0, acc[ti], 0, 0, 0);
            acc[ti] = __builtin_amdgcn_mfma_f32_16x16x32_bf16(a1, b1, acc[ti], 0, 0, 0);
        }
    }
    // biases + mask: lane holds q = q0 + quad*4+rg, s = nt*16 + l15
    #pragma unroll
    for (int ti = 0; ti < 16; ti++) {
        int nt = (ti >> 1) * 8 + 4 * (ti & 1) + w;
        int s = nt * 16 + l15;
        float lx = lex[b * L + s];
        bool dead = (mask[b * L + s] == 0);
        #pragma unroll
        for (int rg = 0; rg < 4; rg++) {
            int q = q0 + quad * 4 + rg;
            float lg = acc[ti][rg] * 0.125f
                     + pos_bias[((size_t)h * L + q) * L + s]
                     + postag[((size_t)bh * L + q) * L + s] + lx;
            acc[ti][rg] = dead ? -INFINITY : lg;
        }
    }
    // softmax over s
    float mxv[4], inv_s[4];
    #pragma unroll
    for (int rg = 0; rg < 4; rg++) {
        float mx = -INFINITY;
        #pragma unroll
        for (int ti = 0; ti < 16; ti++) mx = fmaxf(mx, acc[ti][rg]);
        #pragma unroll
        for (int m = 1; m <= 8; m <<= 1) mx = fmaxf(mx, __shfl_xor(mx, m, 64));
        if (l15 == 0) redA[quad * 4 + rg][w] = mx;
    }
    __syncthreads();
    #pragma unroll
    for (int rg = 0; rg < 4; rg++) {
        int q = quad * 4 + rg;
        mxv[rg] = fmaxf(fmaxf(redA[q][0], redA[q][1]), fmaxf(redA[q][2], redA[q][3]));
        float sum = 0.f;
        #pragma unroll
        for (int ti = 0; ti < 16; ti++) {
            float e = __expf(acc[ti][rg] - mxv[rg]);
            acc[ti][rg] = e;
            sum += e;
        }
        #pragma unroll
        for (int m = 1; m <= 8; m <<= 1) sum += __shfl_xor(sum, m, 64);
        if (l15 == 0) redB[q][w] = sum;
    }
    __syncthreads();
    #pragma unroll
    for (int rg = 0; rg < 4; rg++) {
        int q = quad * 4 + rg;
        inv_s[rg] = 1.0f / (redB[q][0] + redB[q][1] + redB[q][2] + redB[q][3]);
    }
    #pragma unroll
    for (int ti = 0; ti < 16; ti++) {
        int nt = (ti >> 1) * 8 + 4 * (ti & 1) + w;
        int s = nt * 16 + l15;
        #pragma unroll
        for (int rg = 0; rg < 4; rg++) {
            int q = quad * 4 + rg;
            attn_out[((size_t)bh * L + q0 + q) * L + s] = acc[ti][rg] * inv_s[rg];
        }
    }
}

// ---------------- batched GEMM, 128m x 64n tile, BK=64 ---------------------
// C = A @ W^T (+bias) (+res). A fp32 (converted during staging) or bf16.
// CTX_OUT: C offset = (z>>4)*L*D + (z&15)*64 (ctx head-interleave), else z=0.
template<bool A_FP32, bool OUT_BF16, bool HAS_BIAS, bool ADD_RES, bool CTX_OUT>
__global__ __launch_bounds__(256) void gemm_n64(
        const void* __restrict__ Av, size_t strideAz,
        const unsigned short* __restrict__ W, size_t strideWz,
        const float* __restrict__ bias, const float* __restrict__ res,
        void* __restrict__ Cv, int ldc, int Kk) {
    __shared__ __align__(16) unsigned short As[128][72];
    __shared__ __align__(16) unsigned short Ws[64][72];
    int t = threadIdx.x, lane = t & 63, w = t >> 6;
    int quad = lane >> 4, l15 = lane & 15;
    int bm = blockIdx.x * 128, bn = blockIdx.y * 64, z = blockIdx.z;
    int wm = (w >> 1) * 64, wn = (w & 1) * 32;
    int r0 = t >> 3, c8 = t & 7;
    const unsigned short* Wp = W + (size_t)z * strideWz;
    f32x4 acc[4][2] = {};
    for (int k0 = 0; k0 < Kk; k0 += 64) {
        __syncthreads();
        if (A_FP32) {
            const float* A = (const float*)Av + (size_t)z * strideAz;
            #pragma unroll
            for (int i = 0; i < 4; i++) {
                int rr = r0 + 32 * i;
                const float* src = &A[(size_t)(bm + rr) * Kk + k0 + c8 * 8];
                float4 f0 = *(const float4*)src;
                float4 f1 = *(const float4*)(src + 4);
                ushort4 u0, u1;
                u0.x = f2bf(f0.x); u0.y = f2bf(f0.y); u0.z = f2bf(f0.z); u0.w = f2bf(f0.w);
                u1.x = f2bf(f1.x); u1.y = f2bf(f1.y); u1.z = f2bf(f1.z); u1.w = f2bf(f1.w);
                *(ushort4*)&As[rr][c8 * 8]     = u0;
                *(ushort4*)&As[rr][c8 * 8 + 4] = u1;
            }
        } else {
            const unsigned short* A = (const unsigned short*)Av + (size_t)z * strideAz;
            #pragma unroll
            for (int i = 0; i < 4; i++) {
                int rr = r0 + 32 * i;
                *(uint4*)&As[rr][c8 * 8] = *(const uint4*)&A[(size_t)(bm + rr) * Kk + k0 + c8 * 8];
            }
        }
        #pragma unroll
        for (int i = 0; i < 2; i++) {
            int rr = r0 + 32 * i;
            *(uint4*)&Ws[rr][c8 * 8] = *(const uint4*)&Wp[(size_t)(bn + rr) * Kk + k0 + c8 * 8];
        }
        __syncthreads();
        #pragma unroll
        for (int k2 = 0; k2 < 64; k2 += 32) {
            bf16x8 av[4], bw[2];
            #pragma unroll
            for (int i = 0; i < 4; i++)
                av[i] = *(const bf16x8*)&As[wm + i * 16 + l15][k2 + quad * 8];
            #pragma unroll
            for (int j = 0; j < 2; j++)
                bw[j] = *(const bf16x8*)&Ws[wn + j * 16 + l15][k2 + quad * 8];
            #pragma unroll
            for (int i = 0; i < 4; i++)
                #pragma unroll
                for (int j = 0; j < 2; j++)
                    acc[i][j] = __builtin_amdgcn_mfma_f32_16x16x32_bf16(av[i], bw[j], acc[i][j], 0, 0, 0);
        }
    }
    size_t coff = CTX_OUT ? ((size_t)(z >> 4) * L * D + (size_t)(z & 15) * 64) : 0;
    #pragma unroll
    for (int j = 0; j < 2; j++) {
        int col = bn + wn + j * 16 + l15;
        float bcol = HAS_BIAS ? bias[col] : 0.f;
        #pragma unroll
        for (int i = 0; i < 4; i++)
            #pragma unroll
            for (int rg = 0; rg < 4; rg++) {
                int row = bm + wm + i * 16 + quad * 4 + rg;
                float v = acc[i][j][rg] + bcol;
                if (ADD_RES) v += res[(size_t)row * ldc + col];
                if (OUT_BF16)
                    ((unsigned short*)Cv)[coff + (size_t)row * ldc + col] = f2bf(v);
                else
                    ((float*)Cv)[coff + (size_t)row * ldc + col] = v;
            }
    }
}

extern "C" void kernel_launch(void* const* d_in, const int* in_sizes, int n_in,
                              void* d_out, int out_size, void* d_ws, size_t ws_size,
                              hipStream_t stream) {
    (void)in_sizes; (void)n_in; (void)out_size; (void)ws_size;
    const float* query  = (const float*)d_in[0];
    const float* pos_b  = (const float*)d_in[1];
    const float* postag = (const float*)d_in[2];
    const float* lex    = (const float*)d_in[3];
    const int*   mask   = (const int*)d_in[4];
    const float* Wq = (const float*)d_in[5];
    const float* bq = (const float*)d_in[6];
    const float* Wk = (const float*)d_in[7];
    const float* bk = (const float*)d_in[8];
    const float* Wv = (const float*)d_in[9];
    const float* bv = (const float*)d_in[10];
    const float* Wo = (const float*)d_in[11];
    const float* bo = (const float*)d_in[12];
    const float* gamma = (const float*)d_in[13];
    const float* beta  = (const float*)d_in[14];

    float* out  = (float*)d_out;                 // (B,L,D)
    float* attn = out + (size_t)B * L * D;       // (B,H,L,L)

    unsigned short* ws16 = (unsigned short*)d_ws;
    const size_t NE = (size_t)M * D;             // 2M elements
    unsigned short* qn16  = ws16;
    unsigned short* q16   = ws16 + NE;
    unsigned short* W16   = ws16 + 2 * NE;       // 4*DD
    unsigned short* Qm16  = W16 + 4 * (size_t)DD;
    unsigned short* Km16  = Qm16 + NE;
    unsigned short* Vm16  = Km16 + NE;
    unsigned short* Vt16  = Vm16 + NE;           // [32][64][1024]
    unsigned short* ctx16 = Vt16 + NE;

    ln2_kernel<<<M, 256, 0, stream>>>(query, gamma, beta, qn16, q16);
    wconv_kernel<<<dim3(DD / 1024, 4), 256, 0, stream>>>(Wq, Wk, Wv, Wo, W16);
    gemm_qkv<<<dim3(24, 16), 256, 0, stream>>>(qn16, q16, W16, bq, bk, bv,
                                               Qm16, Km16, Vm16);
    vtrans_kernel<<<dim3(8, 32), 256, 0, stream>>>(Vm16, Vt16);
    attn3_kernel<<<B * H * (L / 16), 256, 0, stream>>>(Qm16, Km16, pos_b, postag,
                                                       lex, mask, attn);
    // ctx = attn @ Vt^T  (batched over bh)
    gemm_n64<true, true, false, false, true><<<dim3(8, 1, 32), 256, 0, stream>>>(
        attn, (size_t)L * L, Vt16, (size_t)64 * L, nullptr, nullptr, ctx16, D, L);
    // out = ctx @ Wo^T + bo + query
    gemm_n64<false, false, true, true, false><<<dim3(16, 16, 1), 256, 0, stream>>>(
        ctx16, 0, W16 + 3 * (size_t)DD, 0, bo, query, out, D, D);
}

// Round 4
// 505.251 us; speedup vs baseline: 2.1485x; 1.0542x over previous
//
#include <hip/hip_runtime.h>
#include <hip/hip_bf16.h>
#include <math.h>

constexpr int B = 2, L = 1024, D = 1024, H = 16, DK = 64;
constexpr int M = B * L;           // 2048 rows
constexpr int DD = D * D;

typedef __attribute__((ext_vector_type(8))) short bf16x8;
typedef __attribute__((ext_vector_type(4))) float f32x4;

__device__ inline unsigned short f2bf(float f) {
    __hip_bfloat16 h = __float2bfloat16(f);
    return __builtin_bit_cast(unsigned short, h);
}

// async global->LDS, 16B per lane; LDS dest = base + lane*16 (wave-uniform base)
__device__ inline void glds16(const void* g, void* l) {
    __builtin_amdgcn_global_load_lds((const __attribute__((address_space(1))) void*)g,
                                     (__attribute__((address_space(3))) void*)l,
                                     16, 0, 0);
}

// ---------------- LayerNorm: qn16 = LN(query) bf16, q16 = bf16(query) -------
__global__ __launch_bounds__(256) void ln2_kernel(const float* __restrict__ x,
                                                  const float* __restrict__ gamma,
                                                  const float* __restrict__ beta,
                                                  unsigned short* __restrict__ qn16,
                                                  unsigned short* __restrict__ q16) {
    int row = blockIdx.x;
    int t = threadIdx.x;
    const float4 v = ((const float4*)(x + (size_t)row * D))[t];
    float s  = v.x + v.y + v.z + v.w;
    float sq = v.x*v.x + v.y*v.y + v.z*v.z + v.w*v.w;
    #pragma unroll
    for (int m = 32; m >= 1; m >>= 1) {
        s  += __shfl_xor(s, m, 64);
        sq += __shfl_xor(sq, m, 64);
    }
    __shared__ float rs[4], rq[4];
    int wid = t >> 6;
    if ((t & 63) == 0) { rs[wid] = s; rq[wid] = sq; }
    __syncthreads();
    s  = rs[0] + rs[1] + rs[2] + rs[3];
    sq = rq[0] + rq[1] + rq[2] + rq[3];
    float mean = s * (1.0f / D);
    float var  = sq * (1.0f / D) - mean * mean;
    float rstd = rsqrtf(var + 1e-6f);
    float4 g  = ((const float4*)gamma)[t];
    float4 bb = ((const float4*)beta)[t];
    ushort4 on, oq;
    on.x = f2bf((v.x - mean) * rstd * g.x + bb.x);
    on.y = f2bf((v.y - mean) * rstd * g.y + bb.y);
    on.z = f2bf((v.z - mean) * rstd * g.z + bb.z);
    on.w = f2bf((v.w - mean) * rstd * g.w + bb.w);
    oq.x = f2bf(v.x); oq.y = f2bf(v.y); oq.z = f2bf(v.z); oq.w = f2bf(v.w);
    ((ushort4*)(qn16 + (size_t)row * D))[t] = on;
    ((ushort4*)(q16  + (size_t)row * D))[t] = oq;
}

// ---------------- weight cast: 4 x (D,D) fp32 -> bf16 ----------------------
__global__ __launch_bounds__(256) void wconv_kernel(const float* __restrict__ Wq,
                                                    const float* __restrict__ Wk,
                                                    const float* __restrict__ Wv,
                                                    const float* __restrict__ Wo,
                                                    unsigned short* __restrict__ out) {
    const float* src = (blockIdx.y == 0) ? Wq : (blockIdx.y == 1) ? Wk
                       : (blockIdx.y == 2) ? Wv : Wo;
    size_t i = (size_t)blockIdx.x * 256 + threadIdx.x;
    float4 v = ((const float4*)src)[i];
    ushort4 o;
    o.x = f2bf(v.x); o.y = f2bf(v.y); o.z = f2bf(v.z); o.w = f2bf(v.w);
    ((ushort4*)(out + (size_t)blockIdx.y * DD))[i] = o;
}

// ---------------- fused QKV GEMM: 128x128 tile, BK=64, global_load_lds ------
// Swizzled LDS: phys chunk = logical chunk ^ (row&7); rows of 64 shorts, no pad.
__global__ __launch_bounds__(256) void gemm_qkv(
        const unsigned short* __restrict__ qn16, const unsigned short* __restrict__ q16,
        const unsigned short* __restrict__ W,
        const float* __restrict__ bq, const float* __restrict__ bk,
        const float* __restrict__ bv,
        unsigned short* __restrict__ Qm, unsigned short* __restrict__ Km,
        unsigned short* __restrict__ Vm) {
    __shared__ __align__(16) unsigned short As[128 * 64];
    __shared__ __align__(16) unsigned short Ws[128 * 64];
    int t = threadIdx.x, lane = t & 63, w = t >> 6;
    int quad = lane >> 4, l15 = lane & 15;
    int nt = blockIdx.x;                 // 0..23
    int bm = blockIdx.y * 128;
    const unsigned short* A = (nt < 8) ? qn16 : q16;
    const float* bias = (nt < 8) ? bq : ((nt < 16) ? bk : bv);
    unsigned short* Cout = (nt < 8) ? Qm : ((nt < 16) ? Km : Vm);
    int bn_local = (nt & 7) * 128;
    int wm = (w >> 1) * 64, wn = (w & 1) * 64;
    f32x4 acc[4][4] = {};
    for (int k0 = 0; k0 < D; k0 += 64) {
        __syncthreads();
        const unsigned short* ap = A + (size_t)(bm + w * 32) * D + k0;
        const unsigned short* wp = W + (size_t)(nt * 128 + w * 32) * D + k0;
        #pragma unroll
        for (int i = 0; i < 4; i++) {
            int c = i * 64 + lane;
            int r = c >> 3, g = (c & 7) ^ (r & 7);
            glds16(ap + (size_t)r * D + g * 8, &As[w * 2048 + i * 512]);
            glds16(wp + (size_t)r * D + g * 8, &Ws[w * 2048 + i * 512]);
        }
        __syncthreads();
        #pragma unroll
        for (int k2 = 0; k2 < 2; k2++) {
            bf16x8 av[4], bw[4];
            #pragma unroll
            for (int i = 0; i < 4; i++) {
                int r = wm + i * 16 + l15;
                av[i] = *(const bf16x8*)&As[r * 64 + (((quad + 4 * k2) ^ (r & 7)) * 8)];
            }
            #pragma unroll
            for (int j = 0; j < 4; j++) {
                int r = wn + j * 16 + l15;
                bw[j] = *(const bf16x8*)&Ws[r * 64 + (((quad + 4 * k2) ^ (r & 7)) * 8)];
            }
            #pragma unroll
            for (int i = 0; i < 4; i++)
                #pragma unroll
                for (int j = 0; j < 4; j++)
                    acc[i][j] = __builtin_amdgcn_mfma_f32_16x16x32_bf16(av[i], bw[j], acc[i][j], 0, 0, 0);
        }
    }
    #pragma unroll
    for (int j = 0; j < 4; j++) {
        int col = bn_local + wn + j * 16 + l15;
        float bcol = bias[col];
        #pragma unroll
        for (int i = 0; i < 4; i++)
            #pragma unroll
            for (int rg = 0; rg < 4; rg++) {
                int row = bm + wm + i * 16 + quad * 4 + rg;
                Cout[(size_t)row * D + col] = f2bf(acc[i][j][rg] + bcol);
            }
    }
}

// ---------------- V transpose: Vm [b,s,h*64+d] -> Vt [bh][d][s] ------------
__global__ __launch_bounds__(256) void vtrans_kernel(const unsigned short* __restrict__ Vm,
                                                     unsigned short* __restrict__ Vt) {
    __shared__ unsigned short sb[128 * 66];
    int t = threadIdx.x;
    int z = blockIdx.y;
    int b = z >> 4, h = z & 15;
    int s0 = blockIdx.x * 128;
    size_t base = (size_t)b * L * D + (size_t)h * 64;
    #pragma unroll
    for (int i = 0; i < 4; i++) {
        int idx = t + 256 * i;
        int r = idx >> 3, c8 = idx & 7;
        uint4 vv = *(const uint4*)&Vm[base + (size_t)(s0 + r) * D + c8 * 8];
        unsigned int* sp = (unsigned int*)&sb[r * 66 + c8 * 8];
        sp[0] = vv.x; sp[1] = vv.y; sp[2] = vv.z; sp[3] = vv.w;
    }
    __syncthreads();
    #pragma unroll
    for (int i = 0; i < 4; i++) {
        int idx = t + 256 * i;
        int d = idx >> 4, sc = idx & 15;
        unsigned short tmp[8];
        #pragma unroll
        for (int j = 0; j < 8; j++) tmp[j] = sb[(sc * 8 + j) * 66 + d];
        *(uint4*)&Vt[((size_t)z * 64 + d) * L + s0 + sc * 8] = *(uint4*)tmp;
    }
}

// ---------------- attention: S^T = K Q^T layout, vectorized bias/softmax ----
// Block: (b,h) x 16 queries. Lane holds S^T[s = nt*16+quad*4+rg][q = q0+l15].
__global__ __launch_bounds__(256) void attn4_kernel(
        const unsigned short* __restrict__ Qm, const unsigned short* __restrict__ Km,
        const float* __restrict__ pos_bias, const float* __restrict__ postag,
        const float* __restrict__ lex, const int* __restrict__ mask,
        float* __restrict__ attn_out) {
    __shared__ __align__(16) unsigned short q_sh[16][72];
    __shared__ __align__(16) unsigned short kv_sh[128 * 64];   // swizzled, no pad
    __shared__ float redA[16][4], redB[16][4];

    int t = threadIdx.x, lane = t & 63, w = t >> 6;
    int quad = lane >> 4, l15 = lane & 15;
    int qt = blockIdx.x & 63;
    int bh = blockIdx.x >> 6;
    int b = bh >> 4, h = bh & 15;
    int q0 = qt * 16;
    int q = q0 + l15;
    size_t base = (size_t)b * L * D + (size_t)h * DK;

    if (t < 128) {
        int r = t >> 3, c8 = t & 7;
        *(uint4*)&q_sh[r][c8 * 8] = *(const uint4*)&Qm[base + (size_t)(q0 + r) * D + c8 * 8];
    }
    __syncthreads();
    bf16x8 qb0 = *(const bf16x8*)&q_sh[l15][quad * 8];
    bf16x8 qb1 = *(const bf16x8*)&q_sh[l15][32 + quad * 8];

    f32x4 acc[16] = {};
    // ---- S^T = K Q^T : 8 stages of 128 keys; wave w owns local tiles w, w+4
    for (int st = 0; st < 8; st++) {
        __syncthreads();
        const unsigned short* kp = Km + base + (size_t)(st * 128 + w * 32) * D;
        #pragma unroll
        for (int i = 0; i < 4; i++) {
            int c = i * 64 + lane;
            int r = c >> 3, g = (c & 7) ^ (r & 7);
            glds16(kp + (size_t)r * D + g * 8, &kv_sh[w * 2048 + i * 512]);
        }
        __syncthreads();
        #pragma unroll
        for (int u = 0; u < 2; u++) {
            int r = (u * 4 + w) * 16 + l15;          // s-row within stage
            bf16x8 ka0 = *(const bf16x8*)&kv_sh[r * 64 + ((quad ^ (r & 7)) * 8)];
            bf16x8 ka1 = *(const bf16x8*)&kv_sh[r * 64 + (((quad + 4) ^ (r & 7)) * 8)];
            int ti = 2 * st + u;
            acc[ti] = __builtin_amdgcn_mfma_f32_16x16x32_bf16(ka0, qb0, acc[ti], 0, 0, 0);
            acc[ti] = __builtin_amdgcn_mfma_f32_16x16x32_bf16(ka1, qb1, acc[ti], 0, 0, 0);
        }
    }
    // ---- biases + mask: float4 along s ----
    #pragma unroll
    for (int ti = 0; ti < 16; ti++) {
        int nt = (ti >> 1) * 8 + (ti & 1) * 4 + w;
        int s0 = nt * 16 + quad * 4;
        float4 pb = *(const float4*)&pos_bias[((size_t)h * L + q) * L + s0];
        float4 pt = *(const float4*)&postag[((size_t)bh * L + q) * L + s0];
        float4 lx = *(const float4*)&lex[b * L + s0];
        int4   mk = *(const int4*)&mask[b * L + s0];
        acc[ti][0] = mk.x ? acc[ti][0] * 0.125f + pb.x + pt.x + lx.x : -1e30f;
        acc[ti][1] = mk.y ? acc[ti][1] * 0.125f + pb.y + pt.y + lx.y : -1e30f;
        acc[ti][2] = mk.z ? acc[ti][2] * 0.125f + pb.z + pt.z + lx.z : -1e30f;
        acc[ti][3] = mk.w ? acc[ti][3] * 0.125f + pb.w + pt.w + lx.w : -1e30f;
    }
    // ---- softmax over s: per-lane -> quads (shfl 16,32) -> waves (LDS) ----
    float mx = -1e30f;
    #pragma unroll
    for (int ti = 0; ti < 16; ti++)
        #pragma unroll
        for (int rg = 0; rg < 4; rg++) mx = fmaxf(mx, acc[ti][rg]);
    mx = fmaxf(mx, __shfl_xor(mx, 16, 64));
    mx = fmaxf(mx, __shfl_xor(mx, 32, 64));
    if (quad == 0) redA[l15][w] = mx;
    __syncthreads();
    mx = fmaxf(fmaxf(redA[l15][0], redA[l15][1]), fmaxf(redA[l15][2], redA[l15][3]));
    float sum = 0.f;
    #pragma unroll
    for (int ti = 0; ti < 16; ti++)
        #pragma unroll
        for (int rg = 0; rg < 4; rg++) {
            float e = __expf(acc[ti][rg] - mx);
            acc[ti][rg] = e;
            sum += e;
        }
    sum += __shfl_xor(sum, 16, 64);
    sum += __shfl_xor(sum, 32, 64);
    if (quad == 0) redB[l15][w] = sum;
    __syncthreads();
    float inv = 1.0f / (redB[l15][0] + redB[l15][1] + redB[l15][2] + redB[l15][3]);
    // ---- write attn (float4 along s) ----
    #pragma unroll
    for (int ti = 0; ti < 16; ti++) {
        int nt = (ti >> 1) * 8 + (ti & 1) * 4 + w;
        int s0 = nt * 16 + quad * 4;
        float4 o;
        o.x = acc[ti][0] * inv; o.y = acc[ti][1] * inv;
        o.z = acc[ti][2] * inv; o.w = acc[ti][3] * inv;
        *(float4*)&attn_out[((size_t)bh * L + q) * L + s0] = o;
    }
}

// ---------------- PV GEMM: ctx[bh-tile] = attn(fp32) @ Vt^T, 64x64 tile ----
__global__ __launch_bounds__(256) void gemm_pv(
        const float* __restrict__ attnP, const unsigned short* __restrict__ Vt,
        unsigned short* __restrict__ ctx16) {
    __shared__ __align__(16) unsigned short As[64][72];        // padded (cvt path)
    __shared__ __align__(16) unsigned short Ws[64 * 64];       // swizzled glds
    int t = threadIdx.x, lane = t & 63, w = t >> 6;
    int quad = lane >> 4, l15 = lane & 15;
    int bm = blockIdx.x * 64, z = blockIdx.z;
    int wm = (w >> 1) * 32, wn = (w & 1) * 32;
    int ar = t >> 2, ac = (t & 3) * 16;
    f32x4 acc[2][2] = {};
    for (int k0 = 0; k0 < L; k0 += 64) {
        __syncthreads();
        const unsigned short* wp = Vt + ((size_t)z * 64 + w * 16) * L + k0;
        #pragma unroll
        for (int i = 0; i < 2; i++) {
            int c = i * 64 + lane;
            int r = c >> 3, g = (c & 7) ^ (r & 7);
            glds16(wp + (size_t)r * L + g * 8, &Ws[w * 1024 + i * 512]);
        }
        {   // A: fp32 -> bf16 staging (16 floats/thread)
            const float* ap = &attnP[((size_t)z * L + bm + ar) * L + k0 + ac];
            float4 f0 = *(const float4*)ap;
            float4 f1 = *(const float4*)(ap + 4);
            float4 f2 = *(const float4*)(ap + 8);
            float4 f3 = *(const float4*)(ap + 12);
            ushort4 u0, u1, u2, u3;
            u0.x = f2bf(f0.x); u0.y = f2bf(f0.y); u0.z = f2bf(f0.z); u0.w = f2bf(f0.w);
            u1.x = f2bf(f1.x); u1.y = f2bf(f1.y); u1.z = f2bf(f1.z); u1.w = f2bf(f1.w);
            u2.x = f2bf(f2.x); u2.y = f2bf(f2.y); u2.z = f2bf(f2.z); u2.w = f2bf(f2.w);
            u3.x = f2bf(f3.x); u3.y = f2bf(f3.y); u3.z = f2bf(f3.z); u3.w = f2bf(f3.w);
            *(ushort4*)&As[ar][ac]      = u0;
            *(ushort4*)&As[ar][ac + 4]  = u1;
            *(ushort4*)&As[ar][ac + 8]  = u2;
            *(ushort4*)&As[ar][ac + 12] = u3;
        }
        __syncthreads();
        #pragma unroll
        for (int k2 = 0; k2 < 2; k2++) {
            bf16x8 av[2], bw[2];
            #pragma unroll
            for (int i = 0; i < 2; i++)
                av[i] = *(const bf16x8*)&As[wm + i * 16 + l15][k2 * 32 + quad * 8];
            #pragma unroll
            for (int j = 0; j < 2; j++) {
                int r = wn + j * 16 + l15;
                bw[j] = *(const bf16x8*)&Ws[r * 64 + (((quad + 4 * k2) ^ (r & 7)) * 8)];
            }
            #pragma unroll
            for (int i = 0; i < 2; i++)
                #pragma unroll
                for (int j = 0; j < 2; j++)
                    acc[i][j] = __builtin_amdgcn_mfma_f32_16x16x32_bf16(av[i], bw[j], acc[i][j], 0, 0, 0);
        }
    }
    size_t coff = (size_t)(z >> 4) * L * D + (size_t)(z & 15) * 64;
    #pragma unroll
    for (int i = 0; i < 2; i++)
        #pragma unroll
        for (int j = 0; j < 2; j++)
            #pragma unroll
            for (int rg = 0; rg < 4; rg++) {
                int row = bm + wm + i * 16 + quad * 4 + rg;
                int col = wn + j * 16 + l15;
                ctx16[coff + (size_t)row * D + col] = f2bf(acc[i][j][rg]);
            }
}

// ---------------- out GEMM: out = ctx @ Wo^T + bo + query, 64x64 tile ------
__global__ __launch_bounds__(256) void gemm_out(
        const unsigned short* __restrict__ A, const unsigned short* __restrict__ W,
        const float* __restrict__ bias, const float* __restrict__ res,
        float* __restrict__ C) {
    __shared__ __align__(16) unsigned short As[64 * 64];
    __shared__ __align__(16) unsigned short Ws[64 * 64];
    int t = threadIdx.x, lane = t & 63, w = t >> 6;
    int quad = lane >> 4, l15 = lane & 15;
    int bm = blockIdx.x * 64, bn = blockIdx.y * 64;
    int wm = (w >> 1) * 32, wn = (w & 1) * 32;
    f32x4 acc[2][2] = {};
    for (int k0 = 0; k0 < D; k0 += 64) {
        __syncthreads();
        const unsigned short* ap = A + (size_t)(bm + w * 16) * D + k0;
        const unsigned short* wp = W + (size_t)(bn + w * 16) * D + k0;
        #pragma unroll
        for (int i = 0; i < 2; i++) {
            int c = i * 64 + lane;
            int r = c >> 3, g = (c & 7) ^ (r & 7);
            glds16(ap + (size_t)r * D + g * 8, &As[w * 1024 + i * 512]);
            glds16(wp + (size_t)r * D + g * 8, &Ws[w * 1024 + i * 512]);
        }
        __syncthreads();
        #pragma unroll
        for (int k2 = 0; k2 < 2; k2++) {
            bf16x8 av[2], bw[2];
            #pragma unroll
            for (int i = 0; i < 2; i++) {
                int r = wm + i * 16 + l15;
                av[i] = *(const bf16x8*)&As[r * 64 + (((quad + 4 * k2) ^ (r & 7)) * 8)];
            }
            #pragma unroll
            for (int j = 0; j < 2; j++) {
                int r = wn + j * 16 + l15;
                bw[j] = *(const bf16x8*)&Ws[r * 64 + (((quad + 4 * k2) ^ (r & 7)) * 8)];
            }
            #pragma unroll
            for (int i = 0; i < 2; i++)
                #pragma unroll
                for (int j = 0; j < 2; j++)
                    acc[i][j] = __builtin_amdgcn_mfma_f32_16x16x32_bf16(av[i], bw[j], acc[i][j], 0, 0, 0);
        }
    }
    #pragma unroll
    for (int j = 0; j < 2; j++) {
        int col = bn + wn + j * 16 + l15;
        float bcol = bias[col];
        #pragma unroll
        for (int i = 0; i < 2; i++)
            #pragma unroll
            for (int rg = 0; rg < 4; rg++) {
                int row = bm + wm + i * 16 + quad * 4 + rg;
                C[(size_t)row * D + col] = acc[i][j][rg] + bcol + res[(size_t)row * D + col];
            }
    }
}

extern "C" void kernel_launch(void* const* d_in, const int* in_sizes, int n_in,
                              void* d_out, int out_size, void* d_ws, size_t ws_size,
                              hipStream_t stream) {
    (void)in_sizes; (void)n_in; (void)out_size; (void)ws_size;
    const float* query  = (const float*)d_in[0];
    const float* pos_b  = (const float*)d_in[1];
    const float* postag = (const float*)d_in[2];
    const float* lex    = (const float*)d_in[3];
    const int*   mask   = (const int*)d_in[4];
    const float* Wq = (const float*)d_in[5];
    const float* bq = (const float*)d_in[6];
    const float* Wk = (const float*)d_in[7];
    const float* bk = (const float*)d_in[8];
    const float* Wv = (const float*)d_in[9];
    const float* bv = (const float*)d_in[10];
    const float* Wo = (const float*)d_in[11];
    const float* bo = (const float*)d_in[12];
    const float* gamma = (const float*)d_in[13];
    const float* beta  = (const float*)d_in[14];

    float* out  = (float*)d_out;                 // (B,L,D)
    float* attn = out + (size_t)B * L * D;       // (B,H,L,L)

    unsigned short* ws16 = (unsigned short*)d_ws;
    const size_t NE = (size_t)M * D;
    unsigned short* qn16  = ws16;
    unsigned short* q16   = ws16 + NE;
    unsigned short* W16   = ws16 + 2 * NE;       // 4*DD
    unsigned short* Qm16  = W16 + 4 * (size_t)DD;
    unsigned short* Km16  = Qm16 + NE;
    unsigned short* Vm16  = Km16 + NE;
    unsigned short* Vt16  = Vm16 + NE;           // [32][64][1024]
    unsigned short* ctx16 = Vt16 + NE;

    ln2_kernel<<<M, 256, 0, stream>>>(query, gamma, beta, qn16, q16);
    wconv_kernel<<<dim3(DD / 1024, 4), 256, 0, stream>>>(Wq, Wk, Wv, Wo, W16);
    gemm_qkv<<<dim3(24, 16), 256, 0, stream>>>(qn16, q16, W16, bq, bk, bv,
                                               Qm16, Km16, Vm16);
    vtrans_kernel<<<dim3(8, 32), 256, 0, stream>>>(Vm16, Vt16);
    attn4_kernel<<<B * H * (L / 16), 256, 0, stream>>>(Qm16, Km16, pos_b, postag,
                                                       lex, mask, attn);
    gemm_pv<<<dim3(16, 1, 32), 256, 0, stream>>>(attn, Vt16, ctx16);
    gemm_out<<<dim3(32, 16), 256, 0, stream>>>(ctx16, W16 + 3 * (size_t)DD, bo, query, out);
}